// Round 1
// baseline (3619.585 us; speedup 1.0000x reference)
//
#include <hip/hip_runtime.h>
#include <math.h>

#define NLOC 100
#define DMODEL 512
#define NH 4
#define DKH 128
#define DVH 256
#define DFF 2048
#define NLAYERS 12

// ---------------- workspace layout (float offsets) ----------------
#define WT_OFF   0            // 1110944 floats: repacked conv weights
#define H_OFF    1110944      // 100*512
#define Q_OFF    1162144      // 4*100*128
#define K_OFF    1213344      // 4*100*128
#define V_OFF    1264544      // 4*100*256
#define OC_OFF   1366944      // 100*1024
#define FF_OFF   1469344      // 100*2048
// end 1674144 floats = 6.7 MB

struct WPack { const float* w[10]; };
struct BiasPack { const float* b[10]; };

// ---------------- conv weight repack ----------------
// per layer layout: ((ic4*K2 + kk)*Cout + oc)*4 + c   (ic = ic4*4+c, zero-padded)
__global__ __launch_bounds__(256) void wtransform(WPack wp, float* __restrict__ wt)
{
    const int Cout[10] = {8,16,32,32,64,64,128,128,256,512};
    const int CinR[10] = {3,8,16,32,32,64,64,128,128,256};
    const int Kk[10]   = {3,3,3,3,3,3,3,3,3,2};
    const int off[11]  = {0,288,1440,6048,15264,33696,70560,144288,291744,586656,1110944};
    const int total = 1110944;
    for (int i = blockIdx.x*blockDim.x + threadIdx.x; i < total; i += gridDim.x*blockDim.x) {
        int l = 0;
        while (i >= off[l+1]) ++l;
        int rem = i - off[l];
        int K = Kk[l], K2 = K*K, Co = Cout[l], Cr = CinR[l];
        int c   = rem & 3;
        int rem2 = rem >> 2;
        int oc  = rem2 % Co;
        int rem3 = rem2 / Co;
        int kk  = rem3 % K2;
        int ic4 = rem3 / K2;
        int ic  = ic4*4 + c;
        int ky = kk / K, kx = kk % K;
        float val = 0.f;
        if (ic < Cr) val = wp.w[l][((oc*Cr + ic)*K + ky)*K + kx];
        wt[i] = val;
    }
}

// ---------------- fused conv stack (one block per patch) ----------------
// activations channels-last [s][Cs], Cs multiple of 4; lanes oc-fast.
template<int K>
__device__ __forceinline__ void conv_cl(const float4* __restrict__ in4, float* __restrict__ out,
    const float4* __restrict__ wt4, const float* __restrict__ bias,
    int Cin4, int CsIn4, int Cout, int CsOut, int Win, int spatial, int Wout, bool relu)
{
    const int NT = 1024;
    const int K2 = K*K;
    int sgrps = NT / Cout;
    int S = (spatial + sgrps - 1) / sgrps;   // <= 7
    int oc = threadIdx.x % Cout;
    int sgrp = threadIdx.x / Cout;
    int offs[8];
    bool val[8];
    #pragma unroll
    for (int i = 0; i < 8; ++i) {
        int s = sgrp*S + i;
        val[i] = (i < S) && (s < spatial);
        int sy = s / Wout, sx = s - sy*Wout;
        offs[i] = (sy*Win + sx)*CsIn4;
    }
    float acc[8];
    #pragma unroll
    for (int i = 0; i < 8; ++i) acc[i] = 0.f;
    const float4* wp = wt4 + oc;
    for (int ic4 = 0; ic4 < Cin4; ++ic4) {
        #pragma unroll
        for (int kk = 0; kk < K2; ++kk) {
            float4 wv = wp[(ic4*K2 + kk)*Cout];
            int koff = ((kk/K)*Win + (kk%K))*CsIn4 + ic4;
            #pragma unroll
            for (int i = 0; i < 8; ++i) if (val[i]) {
                float4 iv = in4[offs[i] + koff];
                acc[i] += iv.x*wv.x + iv.y*wv.y + iv.z*wv.z + iv.w*wv.w;
            }
        }
    }
    float bv = bias[oc];
    #pragma unroll
    for (int i = 0; i < 8; ++i) if (val[i]) {
        float v = acc[i] + bv;
        if (relu) v = fmaxf(v, 0.f);
        int s = sgrp*S + i;
        out[s*CsOut + oc] = v;
    }
}

__global__ __launch_bounds__(1024) void conv_embed(
    const float* __restrict__ x, const float4* __restrict__ wt4,
    BiasPack bp, float* __restrict__ hout)
{
    __shared__ float4 lds4[3584];          // 56 KB: two ping-pong buffers
    float* b0 = (float*)lds4;              // 7168 floats
    float* b1 = (float*)(lds4 + 1792);
    int p = blockIdx.x;
    int pi = p / 10, pj = p - pi*10;
    int tid = threadIdx.x;
    // stage patch: [s][4], c=3 zero-padded
    for (int t = tid; t < 1600; t += 1024) {
        int s = t >> 2, cch = t & 3;
        int sy = s / 20, sx = s - sy*20;
        float v = 0.f;
        if (cch < 3) v = x[cch*40000 + (pj*20 + sy)*200 + pi*20 + sx];
        b0[t] = v;
    }
    __syncthreads();
    conv_cl<3>((const float4*)b0, b1, wt4 + 0,      bp.b[0], 1,  1,  8,   12,  20, 324, 18, false); __syncthreads();
    conv_cl<3>((const float4*)b1, b0, wt4 + 72,     bp.b[1], 2,  3,  16,  20,  18, 256, 16, true ); __syncthreads();
    conv_cl<3>((const float4*)b0, b1, wt4 + 360,    bp.b[2], 4,  5,  32,  36,  16, 196, 14, false); __syncthreads();
    conv_cl<3>((const float4*)b1, b0, wt4 + 1512,   bp.b[3], 8,  9,  32,  36,  14, 144, 12, true ); __syncthreads();
    conv_cl<3>((const float4*)b0, b1, wt4 + 3816,   bp.b[4], 8,  9,  64,  68,  12, 100, 10, true ); __syncthreads();
    conv_cl<3>((const float4*)b1, b0, wt4 + 8424,   bp.b[5], 16, 17, 64,  68,  10, 64,  8,  true ); __syncthreads();
    conv_cl<3>((const float4*)b0, b1, wt4 + 17640,  bp.b[6], 16, 17, 128, 132, 8,  36,  6,  true ); __syncthreads();
    conv_cl<3>((const float4*)b1, b0, wt4 + 36072,  bp.b[7], 32, 33, 128, 132, 6,  16,  4,  true ); __syncthreads();
    conv_cl<3>((const float4*)b0, b1, wt4 + 72936,  bp.b[8], 32, 33, 256, 260, 4,  4,   2,  true ); __syncthreads();
    conv_cl<2>((const float4*)b1, b0, wt4 + 146664, bp.b[9], 64, 65, 512, 512, 2,  1,   1,  false); __syncthreads();
    if (tid < 512) {
        float val = b0[tid];
        float pos = 20.0f * (float)pi;   // location embedding uses column-block only
        int dd = tid & 255;
        float inv = powf(10000.0f, (2.0f/256.0f) * (float)dd);
        float ang = pos / inv;
        float e = (tid < 256) ? sinf(ang) : cosf(ang);
        hout[p*512 + tid] = val + e;
    }
}

// ---------------- QKV projection ----------------
// grid (8, 25): 256 virtual cols x 4 rows per block. cols: [0,512)=q, [512,1024)=k, [1024,2048)=v
__global__ __launch_bounds__(256) void qkv_kernel(const float* __restrict__ h,
    const float* __restrict__ Wq, const float* __restrict__ Wk, const float* __restrict__ Wv,
    float* __restrict__ q, float* __restrict__ k, float* __restrict__ v, int layer)
{
    __shared__ float4 At[512];             // At[d] = h[r0..r0+3][d]
    int r0 = blockIdx.y * 4;
    int tid = threadIdx.x;
    float* Af = (float*)At;
    for (int t = tid; t < 2048; t += 256) {
        int r = t >> 9, d = t & 511;
        Af[d*4 + r] = h[(size_t)(r0 + r)*512 + d];
    }
    __syncthreads();
    int c = blockIdx.x*256 + tid;
    const float* B; float* out; int str;
    if (c < 512) {
        int hh = c >> 7, kk = c & 127;
        B = Wq + ((size_t)(layer*4 + hh)*512)*128 + kk; str = 128;
        out = q + (size_t)(hh*100 + r0)*128 + kk;
    } else if (c < 1024) {
        int c2 = c - 512; int hh = c2 >> 7, kk = c2 & 127;
        B = Wk + ((size_t)(layer*4 + hh)*512)*128 + kk; str = 128;
        out = k + (size_t)(hh*100 + r0)*128 + kk;
    } else {
        int c2 = c - 1024; int hh = c2 >> 8, dv = c2 & 255;
        B = Wv + ((size_t)(layer*4 + hh)*512)*256 + dv; str = 256;
        out = v + (size_t)(hh*100 + r0)*256 + dv;
    }
    float a0=0.f, a1=0.f, a2=0.f, a3=0.f;
    #pragma unroll 4
    for (int d = 0; d < 512; ++d) {
        float bv = B[(size_t)d*str];
        float4 av = At[d];
        a0 += av.x*bv; a1 += av.y*bv; a2 += av.z*bv; a3 += av.w*bv;
    }
    out[0] = a0; out[str] = a1; out[2*str] = a2; out[3*str] = a3;
}

// ---------------- fused attention: scores+softmax+AV, block per (head, query row) ----------------
__global__ __launch_bounds__(256) void attn_kernel(
    const float* __restrict__ q, const float* __restrict__ kmat,
    const float* __restrict__ v, float* __restrict__ ocat)
{
    __shared__ float qr[128];
    __shared__ float p[100];
    __shared__ float red[2];
    int bx = blockIdx.x;
    int hh = bx / 100, nn = bx - hh*100;
    int t = threadIdx.x;
    if (t < 128) qr[t] = q[(size_t)(hh*100 + nn)*128 + t];
    __syncthreads();
    float sv = 0.f;
    if (t < 100) {
        const float* kp = kmat + (size_t)(hh*100 + t)*128;
        float s0=0.f,s1=0.f,s2=0.f,s3=0.f;
        #pragma unroll 8
        for (int j = 0; j < 128; j += 4) {
            s0 += qr[j]*kp[j]; s1 += qr[j+1]*kp[j+1];
            s2 += qr[j+2]*kp[j+2]; s3 += qr[j+3]*kp[j+3];
        }
        sv = (s0+s1+s2+s3) * 0.1f;    // scale = 1/sqrt(N_LOC) quirk
        p[t] = sv;
    }
    __syncthreads();
    if (t < 64) {
        float m = fmaxf(p[t], (t+64 < 100) ? p[t+64] : -1e30f);
        for (int o = 32; o > 0; o >>= 1) m = fmaxf(m, __shfl_down(m, o));
        if (t == 0) red[0] = m;
    }
    __syncthreads();
    float mx = red[0];
    if (t < 100) p[t] = expf(sv - mx);
    __syncthreads();
    if (t < 64) {
        float s = p[t] + ((t+64 < 100) ? p[t+64] : 0.f);
        for (int o = 32; o > 0; o >>= 1) s += __shfl_down(s, o);
        if (t == 0) red[1] = s;
    }
    __syncthreads();
    float inv = 1.0f / red[1];
    const float* vp = v + (size_t)(hh*100)*256 + t;   // t = dv
    float acc = 0.f;
    #pragma unroll 4
    for (int m = 0; m < 100; ++m) acc += p[m] * vp[(size_t)m*256];
    ocat[(size_t)nn*1024 + hh*256 + t] = acc * inv;
}

// ---------------- generic rows-in-LDS GEMM (K chunk of 512) ----------------
// C[r0..r0+3][c] (+)= A[r0..r0+3][k0..k0+511] @ B[k0..][c]  (+bias at kz==0, optional relu, atomic add mode)
__global__ __launch_bounds__(256) void gemm_rb(
    const float* __restrict__ A, int lda,
    const float* __restrict__ B, int ldb,
    const float* __restrict__ bias,
    float* __restrict__ C, int ldc,
    int addmode, int relu)
{
    __shared__ float4 At[512];
    int r0 = blockIdx.y * 4;
    int k0 = blockIdx.z * 512;
    int tid = threadIdx.x;
    float* Af = (float*)At;
    for (int t = tid; t < 2048; t += 256) {
        int r = t >> 9, d = t & 511;
        Af[d*4 + r] = A[(size_t)(r0 + r)*lda + k0 + d];
    }
    __syncthreads();
    int c = blockIdx.x*256 + tid;
    const float* Bp = B + (size_t)k0*ldb + c;
    float a0=0.f, a1=0.f, a2=0.f, a3=0.f;
    #pragma unroll 4
    for (int d = 0; d < 512; ++d) {
        float bv = Bp[(size_t)d*ldb];
        float4 av = At[d];
        a0 += av.x*bv; a1 += av.y*bv; a2 += av.z*bv; a3 += av.w*bv;
    }
    if (bias && blockIdx.z == 0) {
        float bb = bias[c];
        a0 += bb; a1 += bb; a2 += bb; a3 += bb;
    }
    if (relu) { a0 = fmaxf(a0,0.f); a1 = fmaxf(a1,0.f); a2 = fmaxf(a2,0.f); a3 = fmaxf(a3,0.f); }
    float* cp = C + (size_t)r0*ldc + c;
    if (addmode) {
        atomicAdd(cp, a0); atomicAdd(cp + ldc, a1);
        atomicAdd(cp + 2*ldc, a2); atomicAdd(cp + 3*ldc, a3);
    } else {
        cp[0] = a0; cp[ldc] = a1; cp[2*ldc] = a2; cp[3*ldc] = a3;
    }
}

// ---------------- launch ----------------
extern "C" void kernel_launch(void* const* d_in, const int* in_sizes, int n_in,
                              void* d_out, int out_size, void* d_ws, size_t ws_size,
                              hipStream_t stream)
{
    const float* x = (const float*)d_in[0];
    WPack wpk; BiasPack bpk;
    for (int i = 0; i < 10; ++i) {
        wpk.w[i] = (const float*)d_in[1 + 2*i];
        bpk.b[i] = (const float*)d_in[2 + 2*i];
    }
    const float* Wq = (const float*)d_in[21];
    const float* Wk = (const float*)d_in[22];
    const float* Wv = (const float*)d_in[23];
    const float* Wo = (const float*)d_in[24];
    const float* W1 = (const float*)d_in[25];
    const float* b1 = (const float*)d_in[26];
    const float* W2 = (const float*)d_in[27];
    const float* b2 = (const float*)d_in[28];

    float* ws   = (float*)d_ws;
    float* wt   = ws + WT_OFF;
    float* h    = ws + H_OFF;
    float* qb   = ws + Q_OFF;
    float* kb   = ws + K_OFF;
    float* vb   = ws + V_OFF;
    float* ocat = ws + OC_OFF;
    float* ffn  = ws + FF_OFF;

    wtransform<<<4340, 256, 0, stream>>>(wpk, wt);
    conv_embed<<<100, 1024, 0, stream>>>(x, (const float4*)wt, bpk, h);

    for (int n = 0; n < NLAYERS; ++n) {
        qkv_kernel<<<dim3(8, 25), 256, 0, stream>>>(h, Wq, Wk, Wv, qb, kb, vb, n);
        attn_kernel<<<400, 256, 0, stream>>>(qb, kb, vb, ocat);
        // h += ocat @ Wo[n]   (M=100, N=512, K=1024 split in 2)
        gemm_rb<<<dim3(2, 25, 2), 256, 0, stream>>>(ocat, 1024, Wo + (size_t)n*1024*512, 512,
                                                    nullptr, h, 512, 1, 0);
        // ffn = relu(h @ W1[n] + b1[n])   (M=100, N=2048, K=512)
        gemm_rb<<<dim3(8, 25, 1), 256, 0, stream>>>(h, 512, W1 + (size_t)n*512*2048, 2048,
                                                    b1 + (size_t)n*2048, ffn, 2048, 0, 1);
        // h += ffn @ W2[n] + b2[n]   (M=100, N=512, K=2048 split in 4)
        gemm_rb<<<dim3(2, 25, 4), 256, 0, stream>>>(ffn, 2048, W2 + (size_t)n*2048*512, 512,
                                                    b2 + (size_t)n*512, h, 512, 1, 0);
    }
    hipMemcpyAsync(d_out, h, (size_t)NLOC*DMODEL*sizeof(float),
                   hipMemcpyDeviceToDevice, stream);
}

// Round 2
// 1256.744 us; speedup vs baseline: 2.8801x; 2.8801x over previous
//
#include <hip/hip_runtime.h>
#include <math.h>

#define NLOC 100

typedef __attribute__((ext_vector_type(8))) _Float16 half8;
typedef __attribute__((ext_vector_type(4))) float f32x4;

// ---------------- workspace layout (float offsets) ----------------
#define WT_OFF    0            // 1110944 conv weights repacked (fp32)
#define XP_OFF    1110944      // 160000: padded patch input [100][20][20][4]
#define ACTA_OFF  1270944      // 655360
#define ACTB_OFF  1926304      // 655360
#define H_OFF     2581664      // 51200 fp32
#define QKV_OFF   2632864      // 204800 fp32 [100][2048]
#define OCAT_OFF  2837664      // 25600 (100*1024 ushort)
#define FFN_OFF   2863264      // 102400 (100*2048 ushort)
#define WQKVT_OFF 2965664      // 6291456 (12*2048*512 ushort)
#define WOT_OFF   9257120      // 3145728 (12*512*1024 ushort)
#define W1T_OFF   12402848     // 6291456
#define W2T_OFF   18694304     // 6291456
// end: 24985760 floats = 99.9 MB

struct WPack { const float* w[10]; };

// ---------------- conv weight repack (unchanged layout) ----------------
// per layer: ((ic4*K2 + kk)*Cout + oc)*4 + c   (ic = ic4*4+c, zero-padded)
__global__ __launch_bounds__(256) void wtransform(WPack wp, float* __restrict__ wt)
{
    const int Cout[10] = {8,16,32,32,64,64,128,128,256,512};
    const int CinR[10] = {3,8,16,32,32,64,64,128,128,256};
    const int Kk[10]   = {3,3,3,3,3,3,3,3,3,2};
    const int off[11]  = {0,288,1440,6048,15264,33696,70560,144288,291744,586656,1110944};
    const int total = 1110944;
    for (int i = blockIdx.x*blockDim.x + threadIdx.x; i < total; i += gridDim.x*blockDim.x) {
        int l = 0;
        while (i >= off[l+1]) ++l;
        int rem = i - off[l];
        int K = Kk[l], K2 = K*K, Co = Cout[l], Cr = CinR[l];
        int c   = rem & 3;
        int rem2 = rem >> 2;
        int oc  = rem2 % Co;
        int rem3 = rem2 / Co;
        int kk  = rem3 % K2;
        int ic4 = rem3 / K2;
        int ic  = ic4*4 + c;
        int ky = kk / K, kx = kk % K;
        float val = 0.f;
        if (ic < Cr) val = wp.w[l][((oc*Cr + ic)*K + ky)*K + kx];
        wt[i] = val;
    }
}

// ---------------- stage x -> padded channels-last patches ----------------
__global__ __launch_bounds__(256) void stage_xp(const float* __restrict__ x, float* __restrict__ xp)
{
    int idx = blockIdx.x*256 + threadIdx.x;
    if (idx >= 160000) return;
    int c = idx & 3;
    int idx2 = idx >> 2;
    int p = idx2 / 400;
    int rr = idx2 - p*400;
    int y = rr / 20, xx = rr - y*20;
    int pi = p/10, pj = p - pi*10;
    float v = 0.f;
    if (c < 3) v = x[c*40000 + (pj*20 + y)*200 + pi*20 + xx];
    xp[idx] = v;
}

// ---------------- per-layer conv, thread per output element ----------------
// in: [100][Hin][Win][Cin4] float4; out: [100][Hout][Wout][Cout] float (oc fastest)
template<int KS>
__global__ __launch_bounds__(256) void convL(
    const float4* __restrict__ in, const float4* __restrict__ wt4,
    const float* __restrict__ bias, float* __restrict__ out,
    int Cin4, int Cout, int Hin, int Win, int Hout, int Wout,
    int relu, int addloc, int total)
{
    int idx = blockIdx.x*256 + threadIdx.x;
    if (idx >= total) return;
    const int K2 = KS*KS;
    int oc = idx % Cout;
    int r1 = idx / Cout;
    int HW = Hout*Wout;
    int s = r1 % HW;
    int p = r1 / HW;
    int sy = s / Wout, sx = s - sy*Wout;
    const float4* wp = wt4 + oc;
    const float4* ip = in + ((size_t)(p*Hin + sy)*Win + sx)*Cin4;
    float a0 = 0.f, a1 = 0.f, a2 = 0.f;
    for (int ic4 = 0; ic4 < Cin4; ++ic4) {
        #pragma unroll
        for (int kk = 0; kk < K2; ++kk) {
            float4 wv = wp[(ic4*K2 + kk)*Cout];
            float4 iv = ip[((kk/KS)*Win + (kk%KS))*Cin4 + ic4];
            float d = iv.x*wv.x + iv.y*wv.y + iv.z*wv.z + iv.w*wv.w;
            if ((kk % 3) == 0) a0 += d; else if ((kk % 3) == 1) a1 += d; else a2 += d;
        }
    }
    float v = a0 + a1 + a2 + bias[oc];
    if (relu) v = fmaxf(v, 0.f);
    if (addloc) {
        int pi = p / 10;
        float pos = 20.f * (float)pi;
        int dd = oc & 255;
        float inv = powf(10000.f, (float)dd * (1.f/128.f));
        float ang = pos / inv;
        v += (oc < 256) ? sinf(ang) : cosf(ang);
    }
    out[idx] = v;
}

// ---------------- weight transpose + fp32->f16: src [K][N] -> dst [N][K] ----------------
__global__ __launch_bounds__(256) void wtrans(
    const float* __restrict__ src, unsigned short* __restrict__ dst,
    int K, int N, int matsPerLayer, int dstLayerStride, int dstBase)
{
    __shared__ float t[32][33];
    int mz = blockIdx.z;
    int layer = mz / matsPerLayer;
    int mi = mz - layer*matsPerLayer;
    const float* s = src + (size_t)mz * K * N;
    unsigned short* d = dst + (size_t)layer*dstLayerStride + dstBase + (size_t)mi * N * K;
    int n0 = blockIdx.x*32, k0 = blockIdx.y*32;
    int tx = threadIdx.x & 31, ty = threadIdx.x >> 5;   // ty in [0,8)
    #pragma unroll
    for (int i = 0; i < 32; i += 8) t[ty + i][tx] = s[(size_t)(k0 + ty + i)*N + n0 + tx];
    __syncthreads();
    #pragma unroll
    for (int i = 0; i < 32; i += 8) {
        _Float16 hv = (_Float16)t[tx][ty + i];
        d[(size_t)(n0 + ty + i)*K + k0 + tx] = __builtin_bit_cast(unsigned short, hv);
    }
}

// ---------------- MFMA GEMM: C[100 x N] = A[100 x K] @ Bt^T, wave per 16x16 tile ----------------
// A: fp32 (ABITS=32) or f16 (ABITS=16), row-major lda. Bt: f16 [N][K] row-major.
// grid: (N/64, 7, ksplit); kchunk = K/ksplit.
template<int ABITS, int RELU, int ATOMIC, int STOREH>
__global__ __launch_bounds__(256) void gemm16(
    const void* __restrict__ Av, int lda,
    const unsigned short* __restrict__ Bt, int K,
    const float* __restrict__ bias,
    float* __restrict__ C, unsigned short* __restrict__ Ch, int ldc,
    int kchunk)
{
    int lane = threadIdx.x & 63;
    int wave = threadIdx.x >> 6;
    int mrow = lane & 15, quad = lane >> 4;
    int n0 = blockIdx.x*64 + wave*16;
    int m0 = blockIdx.y*16;
    int arow = m0 + mrow; if (arow > 99) arow = 99;
    int k0 = blockIdx.z * kchunk;
    const unsigned short* bp = Bt + (size_t)(n0 + mrow)*K + quad*8 + k0;
    f32x4 acc = {0.f, 0.f, 0.f, 0.f};
    if (ABITS == 16) {
        const unsigned short* ap = (const unsigned short*)Av + (size_t)arow*lda + quad*8 + k0;
        for (int k = 0; k < kchunk; k += 32) {
            uint4 au = *(const uint4*)(ap + k);
            uint4 bu = *(const uint4*)(bp + k);
            acc = __builtin_amdgcn_mfma_f32_16x16x32_f16(
                __builtin_bit_cast(half8, au), __builtin_bit_cast(half8, bu), acc, 0, 0, 0);
        }
    } else {
        const float* ap = (const float*)Av + (size_t)arow*lda + quad*8 + k0;
        for (int k = 0; k < kchunk; k += 32) {
            float4 f0 = *(const float4*)(ap + k);
            float4 f1 = *(const float4*)(ap + k + 4);
            half8 af;
            af[0] = (_Float16)f0.x; af[1] = (_Float16)f0.y;
            af[2] = (_Float16)f0.z; af[3] = (_Float16)f0.w;
            af[4] = (_Float16)f1.x; af[5] = (_Float16)f1.y;
            af[6] = (_Float16)f1.z; af[7] = (_Float16)f1.w;
            uint4 bu = *(const uint4*)(bp + k);
            acc = __builtin_amdgcn_mfma_f32_16x16x32_f16(
                af, __builtin_bit_cast(half8, bu), acc, 0, 0, 0);
        }
    }
    // C/D: col = lane&15 (n), row = quad*4 + reg (m)
    int n = n0 + mrow;
    float bv = (bias != nullptr && blockIdx.z == 0) ? bias[n] : 0.f;
    #pragma unroll
    for (int r = 0; r < 4; ++r) {
        int row = m0 + quad*4 + r;
        if (row < 100) {
            float v = acc[r] + bv;
            if (RELU) v = fmaxf(v, 0.f);
            if (ATOMIC) atomicAdd(&C[(size_t)row*ldc + n], v);
            else if (C != nullptr) C[(size_t)row*ldc + n] = v;
            if (STOREH) {
                _Float16 hv = (_Float16)v;
                Ch[(size_t)row*ldc + n] = __builtin_bit_cast(unsigned short, hv);
            }
        }
    }
}

// ---------------- attention: block per (head, query row), fp32 ----------------
__global__ __launch_bounds__(256) void attn_kernel(
    const float* __restrict__ qkv, unsigned short* __restrict__ ocat)
{
    __shared__ float qr[128];
    __shared__ float p[100];
    __shared__ float red[2];
    int bx = blockIdx.x;
    int hh = bx / 100, nn = bx - hh*100;
    int t = threadIdx.x;
    if (t < 128) qr[t] = qkv[(size_t)nn*2048 + hh*128 + t];
    __syncthreads();
    float sv = 0.f;
    if (t < 100) {
        const float4* kp = (const float4*)(qkv + (size_t)t*2048 + 512 + hh*128);
        const float4* q4 = (const float4*)qr;
        float s0=0.f, s1=0.f, s2=0.f, s3=0.f;
        #pragma unroll 8
        for (int j = 0; j < 32; ++j) {
            float4 a = q4[j], b = kp[j];
            s0 += a.x*b.x; s1 += a.y*b.y; s2 += a.z*b.z; s3 += a.w*b.w;
        }
        sv = (s0+s1+s2+s3) * 0.1f;    // scale = 1/sqrt(N_LOC) quirk
        p[t] = sv;
    }
    __syncthreads();
    if (t < 64) {
        float m = fmaxf(p[t], (t+64 < 100) ? p[t+64] : -1e30f);
        for (int o = 32; o > 0; o >>= 1) m = fmaxf(m, __shfl_down(m, o));
        if (t == 0) red[0] = m;
    }
    __syncthreads();
    float mx = red[0];
    if (t < 100) p[t] = expf(sv - mx);
    __syncthreads();
    if (t < 64) {
        float s = p[t] + ((t+64 < 100) ? p[t+64] : 0.f);
        for (int o = 32; o > 0; o >>= 1) s += __shfl_down(s, o);
        if (t == 0) red[1] = s;
    }
    __syncthreads();
    float inv = 1.0f / red[1];
    const float* vp = qkv + 1024 + hh*256 + t;       // t = dv in [0,256)
    float acc = 0.f;
    #pragma unroll 4
    for (int m = 0; m < 100; ++m) acc += p[m] * vp[(size_t)m*2048];
    _Float16 hv = (_Float16)(acc * inv);
    ocat[(size_t)nn*1024 + hh*256 + t] = __builtin_bit_cast(unsigned short, hv);
}

// ---------------- launch ----------------
extern "C" void kernel_launch(void* const* d_in, const int* in_sizes, int n_in,
                              void* d_out, int out_size, void* d_ws, size_t ws_size,
                              hipStream_t stream)
{
    const float* x = (const float*)d_in[0];
    WPack wpk;
    const float* cb[10];
    for (int i = 0; i < 10; ++i) {
        wpk.w[i] = (const float*)d_in[1 + 2*i];
        cb[i]    = (const float*)d_in[2 + 2*i];
    }
    const float* Wq = (const float*)d_in[21];
    const float* Wk = (const float*)d_in[22];
    const float* Wv = (const float*)d_in[23];
    const float* Wo = (const float*)d_in[24];
    const float* W1 = (const float*)d_in[25];
    const float* b1 = (const float*)d_in[26];
    const float* W2 = (const float*)d_in[27];
    const float* b2 = (const float*)d_in[28];

    float* ws = (float*)d_ws;
    float* wt  = ws + WT_OFF;
    float* xp  = ws + XP_OFF;
    float* aA  = ws + ACTA_OFF;
    float* aB  = ws + ACTB_OFF;
    float* h   = ws + H_OFF;
    float* qkv = ws + QKV_OFF;
    unsigned short* ocat  = (unsigned short*)(ws + OCAT_OFF);
    unsigned short* ffn   = (unsigned short*)(ws + FFN_OFF);
    unsigned short* wqkvt = (unsigned short*)(ws + WQKVT_OFF);
    unsigned short* wot   = (unsigned short*)(ws + WOT_OFF);
    unsigned short* w1t   = (unsigned short*)(ws + W1T_OFF);
    unsigned short* w2t   = (unsigned short*)(ws + W2T_OFF);

    const float4* cw = (const float4*)wt;

    // weight prep
    wtransform<<<4340, 256, 0, stream>>>(wpk, wt);
    wtrans<<<dim3(4, 16, 48),  256, 0, stream>>>(Wq, wqkvt, 512, 128,  4, 2048*512, 0);
    wtrans<<<dim3(4, 16, 48),  256, 0, stream>>>(Wk, wqkvt, 512, 128,  4, 2048*512, 512*512);
    wtrans<<<dim3(8, 16, 48),  256, 0, stream>>>(Wv, wqkvt, 512, 256,  4, 2048*512, 1024*512);
    wtrans<<<dim3(16, 32, 12), 256, 0, stream>>>(Wo, wot,  1024, 512,  1, 512*1024, 0);
    wtrans<<<dim3(64, 16, 12), 256, 0, stream>>>(W1, w1t,   512, 2048, 1, 2048*512, 0);
    wtrans<<<dim3(16, 64, 12), 256, 0, stream>>>(W2, w2t,  2048, 512,  1, 512*2048, 0);

    // conv stack
    stage_xp<<<625, 256, 0, stream>>>(x, xp);
    convL<3><<<1013, 256, 0, stream>>>((const float4*)xp, cw + 0,      cb[0], aA, 1,  8,   20, 20, 18, 18, 0, 0, 259200);
    convL<3><<<1600, 256, 0, stream>>>((const float4*)aA, cw + 72,     cb[1], aB, 2,  16,  18, 18, 16, 16, 1, 0, 409600);
    convL<3><<<2450, 256, 0, stream>>>((const float4*)aB, cw + 360,    cb[2], aA, 4,  32,  16, 16, 14, 14, 0, 0, 627200);
    convL<3><<<1800, 256, 0, stream>>>((const float4*)aA, cw + 1512,   cb[3], aB, 8,  32,  14, 14, 12, 12, 1, 0, 460800);
    convL<3><<<2500, 256, 0, stream>>>((const float4*)aB, cw + 3816,   cb[4], aA, 8,  64,  12, 12, 10, 10, 1, 0, 640000);
    convL<3><<<1600, 256, 0, stream>>>((const float4*)aA, cw + 8424,   cb[5], aB, 16, 64,  10, 10, 8,  8,  1, 0, 409600);
    convL<3><<<1800, 256, 0, stream>>>((const float4*)aB, cw + 17640,  cb[6], aA, 16, 128, 8,  8,  6,  6,  1, 0, 460800);
    convL<3><<<800,  256, 0, stream>>>((const float4*)aA, cw + 36072,  cb[7], aB, 32, 128, 6,  6,  4,  4,  1, 0, 204800);
    convL<3><<<400,  256, 0, stream>>>((const float4*)aB, cw + 72936,  cb[8], aA, 32, 256, 4,  4,  2,  2,  1, 0, 102400);
    convL<2><<<200,  256, 0, stream>>>((const float4*)aA, cw + 146664, cb[9], h,  64, 512, 2,  2,  1,  1,  0, 1, 51200);

    // transformer
    for (int n = 0; n < 12; ++n) {
        const unsigned short* Bq  = wqkvt + (size_t)n * 2048 * 512;
        const unsigned short* Bo  = wot   + (size_t)n * 512 * 1024;
        const unsigned short* Bf1 = w1t   + (size_t)n * 2048 * 512;
        const unsigned short* Bf2 = w2t   + (size_t)n * 512 * 2048;
        // qkv = h @ Wqkv   [100x2048]
        gemm16<32,0,0,0><<<dim3(32, 7, 1), 256, 0, stream>>>(h, 512, Bq, 512,
            nullptr, qkv, nullptr, 2048, 512);
        attn_kernel<<<400, 256, 0, stream>>>(qkv, ocat);
        // h += ocat @ Wo   (K=1024 split 4)
        gemm16<16,0,1,0><<<dim3(8, 7, 4), 256, 0, stream>>>(ocat, 1024, Bo, 1024,
            nullptr, h, nullptr, 512, 256);
        // ffn = relu(h @ W1 + b1)  -> f16
        gemm16<32,1,0,1><<<dim3(32, 7, 1), 256, 0, stream>>>(h, 512, Bf1, 512,
            b1 + (size_t)n*2048, nullptr, ffn, 2048, 512);
        // h += ffn @ W2 + b2   (K=2048 split 8)
        gemm16<16,0,1,0><<<dim3(8, 7, 8), 256, 0, stream>>>(ffn, 2048, Bf2, 2048,
            b2 + (size_t)n*512, h, nullptr, 512, 256);
    }
    hipMemcpyAsync(d_out, h, (size_t)NLOC*512*sizeof(float),
                   hipMemcpyDeviceToDevice, stream);
}

// Round 3
// 873.791 us; speedup vs baseline: 4.1424x; 1.4383x over previous
//
#include <hip/hip_runtime.h>
#include <math.h>

#define NLOC 100

typedef __attribute__((ext_vector_type(8))) _Float16 half8;
typedef __attribute__((ext_vector_type(4))) float f32x4;

// ---------------- workspace layout (float offsets) ----------------
#define XP_OFF    0            // 160000 f32: padded patches [100][20][20][4]
#define H_OFF     160000       // 51200 f32
#define QKV_OFF   211200       // 204800 f32 [100][2048]
#define OCAT_OFF  416000       // 51200 f32 slots = 100*1024 f16
#define FFN_OFF   467200       // 102400 f32 slots = 100*2048 f16
#define ACTA_OFF  569600       // 320064 f32 slots = 640128 f16
#define ACTB_OFF  889664       // 320064
#define CWH_OFF   1209728      // 555776 f32 slots = 1111552 f16 conv wts L2..L10
#define CW1_OFF   1765504      // 320 f32: conv1 weights as float4[8*9]
#define WQKVT_OFF 1765824      // 6291456 f32 slots (12*2048*512 f16)
#define WOT_OFF   8057280      // 3145728
#define W1T_OFF   11203008     // 6291456
#define W2T_OFF   17494464     // 6291456
// end 23785920 floats = 95.1 MB

struct WPack { const float* w[9]; };   // conv layers 2..10

// ---------------- stage x -> padded channels-last patches ----------------
__global__ __launch_bounds__(256) void stage_xp(const float* __restrict__ x, float* __restrict__ xp)
{
    int idx = blockIdx.x*256 + threadIdx.x;
    if (idx >= 160000) return;
    int c = idx & 3;
    int idx2 = idx >> 2;
    int p = idx2 / 400;
    int rr = idx2 - p*400;
    int y = rr / 20, xx = rr - y*20;
    int pi = p/10, pj = p - pi*10;
    float v = 0.f;
    if (c < 3) v = x[c*40000 + (pj*20 + y)*200 + pi*20 + xx];
    xp[idx] = v;
}

// ---------------- conv1 weight repack: [8][3][3][3] -> float4[oc*9+kk] ----------------
__global__ __launch_bounds__(256) void cw1repack(const float* __restrict__ w, float* __restrict__ w4)
{
    int idx = threadIdx.x;           // 288 = 8*9*4
    if (idx >= 288) return;
    int c = idx & 3;
    int r = idx >> 2;
    int oc = r / 9, kk = r - oc*9;
    int ky = kk/3, kx = kk - ky*3;
    float v = 0.f;
    if (c < 3) v = w[((oc*3 + c)*3 + ky)*3 + kx];
    w4[idx] = v;
}

// ---------------- conv weights L2..L10 -> f16 Bt[oc][Kpad], k = kk*Cin + ic ----------------
__global__ __launch_bounds__(256) void cwrepack(WPack wp, unsigned short* __restrict__ dst)
{
    const int Cin[9]  = {8,16,32,32,64,64,128,128,256};
    const int shift[9]= {3,4,5,5,6,6,7,7,8};
    const int KS[9]   = {3,3,3,3,3,3,3,3,2};
    const int Kpad[9] = {96,160,288,288,576,576,1152,1152,1024};
    const int off[10] = {0,1536,6656,15872,34304,71168,144896,292352,587264,1111552};
    const int total = 1111552;
    for (int i = blockIdx.x*blockDim.x + threadIdx.x; i < total; i += gridDim.x*blockDim.x) {
        int l = 0;
        while (i >= off[l+1]) ++l;
        int rem = i - off[l];
        int kp = Kpad[l];
        int oc = rem / kp;
        int k  = rem - oc*kp;
        int ci = Cin[l];
        int ic = k & (ci - 1);
        int kk = k >> shift[l];
        int ks = KS[l], k2 = ks*ks;
        float v = 0.f;
        if (kk < k2) {
            int ky = kk / ks, kx = kk - ky*ks;
            v = wp.w[l][((oc*ci + ic)*ks + ky)*ks + kx];
        }
        _Float16 hv = (_Float16)v;
        dst[i] = __builtin_bit_cast(unsigned short, hv);
    }
}

// ---------------- conv1: thread per output, fp32 math, f16 out [s][8] ----------------
__global__ __launch_bounds__(256) void conv1k(const float4* __restrict__ xp4,
    const float4* __restrict__ w4, const float* __restrict__ bias, unsigned short* __restrict__ out)
{
    int idx = blockIdx.x*256 + threadIdx.x;
    if (idx >= 259200) return;
    int oc = idx & 7;
    int r = idx >> 3;
    int p = r / 324;
    int s = r - p*324;
    int sy = s / 18, sx = s - sy*18;
    const float4* ip = xp4 + (size_t)(p*20 + sy)*20 + sx;
    float acc = 0.f;
    #pragma unroll
    for (int ky = 0; ky < 3; ++ky)
        #pragma unroll
        for (int kx = 0; kx < 3; ++kx) {
            float4 iv = ip[ky*20 + kx];
            float4 wv = w4[oc*9 + ky*3 + kx];
            acc += iv.x*wv.x + iv.y*wv.y + iv.z*wv.z;
        }
    acc += bias[oc];     // no relu after conv1
    _Float16 hv = (_Float16)acc;
    out[idx] = __builtin_bit_cast(unsigned short, hv);
}

// ---------------- MFMA conv: wave per 16x16 tile, implicit im2col ----------------
// in: f16 [100*Hin*Win][CIN]; wth: f16 [COUT][KPAD]; out: f16 [100*HW][COUT]
template<int CIN, int COUT, int KS, int HIN, int WIN, int HOUT, int WOUT, int KPAD, int RELU, int LAST>
__global__ __launch_bounds__(256) void convM(const unsigned short* __restrict__ in,
    const unsigned short* __restrict__ wth, const float* __restrict__ bias,
    unsigned short* __restrict__ out, float* __restrict__ hout)
{
    constexpr int HW = HOUT*WOUT;
    constexpr int M = 100*HW;
    constexpr int MT = (M + 15)/16;
    constexpr int NT = COUT/16;
    int wave = threadIdx.x >> 6, lane = threadIdx.x & 63;
    int t = blockIdx.x*4 + wave;
    if (t >= MT*NT) return;
    int mt = t % MT, nt = t / MT;
    int mrow = lane & 15, quad = lane >> 4;
    int mg = mt*16 + mrow; if (mg >= M) mg = M - 1;
    int p = mg / HW, s = mg - p*HW;
    int sy = s / WOUT, sx = s - sy*WOUT;
    const unsigned short* ap = in + ((size_t)((p*HIN + sy)*WIN + sx))*CIN;
    const unsigned short* bp = wth + ((size_t)(nt*16 + mrow))*KPAD + quad*8;
    f32x4 acc = {0.f, 0.f, 0.f, 0.f};
    #pragma unroll
    for (int k0 = 0; k0 < KPAD; k0 += 32) {
        int k = k0 + quad*8;
        int kk = k / CIN; if (kk > KS*KS - 1) kk = KS*KS - 1;
        int ky = kk / KS, kx = kk - ky*KS;
        uint4 av = *(const uint4*)(ap + (ky*WIN + kx)*CIN + (k & (CIN-1)));
        uint4 bv = *(const uint4*)(bp + k0);
        acc = __builtin_amdgcn_mfma_f32_16x16x32_f16(
            __builtin_bit_cast(half8, av), __builtin_bit_cast(half8, bv), acc, 0, 0, 0);
    }
    int n = nt*16 + mrow;
    float bv = bias[n];
    #pragma unroll
    for (int r = 0; r < 4; ++r) {
        int m = mt*16 + quad*4 + r;
        if (m < M) {
            float v = acc[r] + bv;
            if (RELU) v = fmaxf(v, 0.f);
            if (LAST) {
                int pi = m / 10;
                float pos = 20.f * (float)pi;
                int dd = n & 255;
                float inv = powf(10000.f, (float)dd * (1.f/128.f));
                float ang = pos / inv;
                v += (n < 256) ? sinf(ang) : cosf(ang);
                hout[(size_t)m*512 + n] = v;
            } else {
                _Float16 hv = (_Float16)v;
                out[(size_t)m*COUT + n] = __builtin_bit_cast(unsigned short, hv);
            }
        }
    }
}

// ---------------- transformer weight transpose fp32->f16: [K][N] -> [N][K] ----------------
__global__ __launch_bounds__(256) void wtrans(
    const float* __restrict__ src, unsigned short* __restrict__ dst,
    int K, int N, int matsPerLayer, int dstLayerStride, int dstBase)
{
    __shared__ float t[32][33];
    int mz = blockIdx.z;
    int layer = mz / matsPerLayer;
    int mi = mz - layer*matsPerLayer;
    const float* s = src + (size_t)mz * K * N;
    unsigned short* d = dst + (size_t)layer*dstLayerStride + dstBase + (size_t)mi * N * K;
    int n0 = blockIdx.x*32, k0 = blockIdx.y*32;
    int tx = threadIdx.x & 31, ty = threadIdx.x >> 5;
    #pragma unroll
    for (int i = 0; i < 32; i += 8) t[ty + i][tx] = s[(size_t)(k0 + ty + i)*N + n0 + tx];
    __syncthreads();
    #pragma unroll
    for (int i = 0; i < 32; i += 8) {
        _Float16 hv = (_Float16)t[tx][ty + i];
        d[(size_t)(n0 + ty + i)*K + k0 + tx] = __builtin_bit_cast(unsigned short, hv);
    }
}

// ---------------- MFMA GEMM (transformer) ----------------
template<int ABITS, int RELU, int ATOMIC, int STOREH>
__global__ __launch_bounds__(256) void gemm16(
    const void* __restrict__ Av, int lda,
    const unsigned short* __restrict__ Bt, int K,
    const float* __restrict__ bias,
    float* __restrict__ C, unsigned short* __restrict__ Ch, int ldc,
    int kchunk)
{
    int lane = threadIdx.x & 63;
    int wave = threadIdx.x >> 6;
    int mrow = lane & 15, quad = lane >> 4;
    int n0 = blockIdx.x*64 + wave*16;
    int m0 = blockIdx.y*16;
    int arow = m0 + mrow; if (arow > 99) arow = 99;
    int k0 = blockIdx.z * kchunk;
    const unsigned short* bp = Bt + (size_t)(n0 + mrow)*K + quad*8 + k0;
    f32x4 acc = {0.f, 0.f, 0.f, 0.f};
    if (ABITS == 16) {
        const unsigned short* ap = (const unsigned short*)Av + (size_t)arow*lda + quad*8 + k0;
        for (int k = 0; k < kchunk; k += 32) {
            uint4 au = *(const uint4*)(ap + k);
            uint4 bu = *(const uint4*)(bp + k);
            acc = __builtin_amdgcn_mfma_f32_16x16x32_f16(
                __builtin_bit_cast(half8, au), __builtin_bit_cast(half8, bu), acc, 0, 0, 0);
        }
    } else {
        const float* ap = (const float*)Av + (size_t)arow*lda + quad*8 + k0;
        for (int k = 0; k < kchunk; k += 32) {
            float4 f0 = *(const float4*)(ap + k);
            float4 f1 = *(const float4*)(ap + k + 4);
            half8 af;
            af[0] = (_Float16)f0.x; af[1] = (_Float16)f0.y;
            af[2] = (_Float16)f0.z; af[3] = (_Float16)f0.w;
            af[4] = (_Float16)f1.x; af[5] = (_Float16)f1.y;
            af[6] = (_Float16)f1.z; af[7] = (_Float16)f1.w;
            uint4 bu = *(const uint4*)(bp + k);
            acc = __builtin_amdgcn_mfma_f32_16x16x32_f16(
                af, __builtin_bit_cast(half8, bu), acc, 0, 0, 0);
        }
    }
    int n = n0 + mrow;
    float bv = (bias != nullptr && blockIdx.z == 0) ? bias[n] : 0.f;
    #pragma unroll
    for (int r = 0; r < 4; ++r) {
        int row = m0 + quad*4 + r;
        if (row < 100) {
            float v = acc[r] + bv;
            if (RELU) v = fmaxf(v, 0.f);
            if (ATOMIC) atomicAdd(&C[(size_t)row*ldc + n], v);
            else if (C != nullptr) C[(size_t)row*ldc + n] = v;
            if (STOREH) {
                _Float16 hv = (_Float16)v;
                Ch[(size_t)row*ldc + n] = __builtin_bit_cast(unsigned short, hv);
            }
        }
    }
}

// ---------------- attention: block per (head, query row) ----------------
__global__ __launch_bounds__(256) void attn_kernel(
    const float* __restrict__ qkv, unsigned short* __restrict__ ocat)
{
    __shared__ float qr[128];
    __shared__ float p[100];
    __shared__ float red[2];
    int bx = blockIdx.x;
    int hh = bx / 100, nn = bx - hh*100;
    int t = threadIdx.x;
    if (t < 128) qr[t] = qkv[(size_t)nn*2048 + hh*128 + t];
    __syncthreads();
    float sv = 0.f;
    if (t < 100) {
        const float4* kp = (const float4*)(qkv + (size_t)t*2048 + 512 + hh*128);
        const float4* q4 = (const float4*)qr;
        float s0=0.f, s1=0.f, s2=0.f, s3=0.f;
        #pragma unroll 8
        for (int j = 0; j < 32; ++j) {
            float4 a = q4[j], b = kp[j];
            s0 += a.x*b.x; s1 += a.y*b.y; s2 += a.z*b.z; s3 += a.w*b.w;
        }
        sv = (s0+s1+s2+s3) * 0.1f;    // scale = 1/sqrt(N_LOC) quirk
        p[t] = sv;
    }
    __syncthreads();
    if (t < 64) {
        float m = fmaxf(p[t], (t+64 < 100) ? p[t+64] : -1e30f);
        for (int o = 32; o > 0; o >>= 1) m = fmaxf(m, __shfl_down(m, o));
        if (t == 0) red[0] = m;
    }
    __syncthreads();
    float mx = red[0];
    if (t < 100) p[t] = expf(sv - mx);
    __syncthreads();
    if (t < 64) {
        float s = p[t] + ((t+64 < 100) ? p[t+64] : 0.f);
        for (int o = 32; o > 0; o >>= 1) s += __shfl_down(s, o);
        if (t == 0) red[1] = s;
    }
    __syncthreads();
    float inv = 1.0f / red[1];
    const float* vp = qkv + 1024 + hh*256 + t;
    float acc = 0.f;
    #pragma unroll 4
    for (int m = 0; m < 100; ++m) acc += p[m] * vp[(size_t)m*2048];
    _Float16 hv = (_Float16)(acc * inv);
    ocat[(size_t)nn*1024 + hh*256 + t] = __builtin_bit_cast(unsigned short, hv);
}

// ---------------- final copy ----------------
__global__ __launch_bounds__(256) void copyk(const float* __restrict__ s, float* __restrict__ d, int n)
{
    int i = blockIdx.x*256 + threadIdx.x;
    if (i < n) d[i] = s[i];
}

// ---------------- launch ----------------
extern "C" void kernel_launch(void* const* d_in, const int* in_sizes, int n_in,
                              void* d_out, int out_size, void* d_ws, size_t ws_size,
                              hipStream_t stream)
{
    const float* x = (const float*)d_in[0];
    const float* cw1 = (const float*)d_in[1];
    const float* cb[10];
    WPack wpk;
    for (int i = 0; i < 10; ++i) cb[i] = (const float*)d_in[2 + 2*i];
    for (int i = 0; i < 9; ++i)  wpk.w[i] = (const float*)d_in[3 + 2*i];  // layers 2..10
    const float* Wq = (const float*)d_in[21];
    const float* Wk = (const float*)d_in[22];
    const float* Wv = (const float*)d_in[23];
    const float* Wo = (const float*)d_in[24];
    const float* W1 = (const float*)d_in[25];
    const float* b1 = (const float*)d_in[26];
    const float* W2 = (const float*)d_in[27];
    const float* b2 = (const float*)d_in[28];

    float* ws = (float*)d_ws;
    float* xp  = ws + XP_OFF;
    float* h   = ws + H_OFF;
    float* qkv = ws + QKV_OFF;
    unsigned short* ocat = (unsigned short*)(ws + OCAT_OFF);
    unsigned short* ffn  = (unsigned short*)(ws + FFN_OFF);
    unsigned short* aA   = (unsigned short*)(ws + ACTA_OFF);
    unsigned short* aB   = (unsigned short*)(ws + ACTB_OFF);
    unsigned short* cwh  = (unsigned short*)(ws + CWH_OFF);
    float* cw14 = ws + CW1_OFF;
    unsigned short* wqkvt = (unsigned short*)(ws + WQKVT_OFF);
    unsigned short* wot   = (unsigned short*)(ws + WOT_OFF);
    unsigned short* w1t   = (unsigned short*)(ws + W1T_OFF);
    unsigned short* w2t   = (unsigned short*)(ws + W2T_OFF);

    // weight prep
    cw1repack<<<2, 256, 0, stream>>>(cw1, cw14);
    cwrepack<<<2172, 256, 0, stream>>>(wpk, cwh);
    wtrans<<<dim3(4, 16, 48),  256, 0, stream>>>(Wq, wqkvt, 512, 128,  4, 2048*512, 0);
    wtrans<<<dim3(4, 16, 48),  256, 0, stream>>>(Wk, wqkvt, 512, 128,  4, 2048*512, 512*512);
    wtrans<<<dim3(8, 16, 48),  256, 0, stream>>>(Wv, wqkvt, 512, 256,  4, 2048*512, 1024*512);
    wtrans<<<dim3(16, 32, 12), 256, 0, stream>>>(Wo, wot,  1024, 512,  1, 512*1024, 0);
    wtrans<<<dim3(64, 16, 12), 256, 0, stream>>>(W1, w1t,   512, 2048, 1, 2048*512, 0);
    wtrans<<<dim3(16, 64, 12), 256, 0, stream>>>(W2, w2t,  2048, 512,  1, 512*2048, 0);

    // conv stack
    stage_xp<<<625, 256, 0, stream>>>(x, xp);
    conv1k<<<1013, 256, 0, stream>>>((const float4*)xp, (const float4*)cw14, cb[0], aA);
    convM<8,  16, 3,18,18,16,16,  96,1,0><<<400, 256, 0, stream>>>(aA, cwh + 0,      cb[1], aB, nullptr);
    convM<16, 32, 3,16,16,14,14, 160,0,0><<<613, 256, 0, stream>>>(aB, cwh + 1536,   cb[2], aA, nullptr);
    convM<32, 32, 3,14,14,12,12, 288,1,0><<<450, 256, 0, stream>>>(aA, cwh + 6656,   cb[3], aB, nullptr);
    convM<32, 64, 3,12,12,10,10, 288,1,0><<<625, 256, 0, stream>>>(aB, cwh + 15872,  cb[4], aA, nullptr);
    convM<64, 64, 3,10,10, 8, 8, 576,1,0><<<400, 256, 0, stream>>>(aA, cwh + 34304,  cb[5], aB, nullptr);
    convM<64,128, 3, 8, 8, 6, 6, 576,1,0><<<450, 256, 0, stream>>>(aB, cwh + 71168,  cb[6], aA, nullptr);
    convM<128,128,3, 6, 6, 4, 4,1152,1,0><<<200, 256, 0, stream>>>(aA, cwh + 144896, cb[7], aB, nullptr);
    convM<128,256,3, 4, 4, 2, 2,1152,1,0><<<100, 256, 0, stream>>>(aB, cwh + 292352, cb[8], aA, nullptr);
    convM<256,512,2, 2, 2, 1, 1,1024,0,1><<<56,  256, 0, stream>>>(aA, cwh + 587264, cb[9], nullptr, h);

    // transformer
    for (int n = 0; n < 12; ++n) {
        const unsigned short* Bq  = wqkvt + (size_t)n * 2048 * 512;
        const unsigned short* Bo  = wot   + (size_t)n * 512 * 1024;
        const unsigned short* Bf1 = w1t   + (size_t)n * 2048 * 512;
        const unsigned short* Bf2 = w2t   + (size_t)n * 512 * 2048;
        gemm16<32,0,0,0><<<dim3(32, 7, 1), 256, 0, stream>>>(h, 512, Bq, 512,
            nullptr, qkv, nullptr, 2048, 512);
        attn_kernel<<<400, 256, 0, stream>>>(qkv, ocat);
        gemm16<16,0,1,0><<<dim3(8, 7, 4), 256, 0, stream>>>(ocat, 1024, Bo, 1024,
            nullptr, h, nullptr, 512, 256);
        gemm16<32,1,0,1><<<dim3(32, 7, 1), 256, 0, stream>>>(h, 512, Bf1, 512,
            b1 + (size_t)n*2048, nullptr, ffn, 2048, 512);
        gemm16<16,0,1,0><<<dim3(8, 7, 8), 256, 0, stream>>>(ffn, 2048, Bf2, 2048,
            b2 + (size_t)n*512, h, nullptr, 512, 256);
    }
    copyk<<<200, 256, 0, stream>>>(h, (float*)d_out, NLOC*512);
}